// Round 7
// baseline (25.366 us; speedup 1.0000x reference)
//
#include <hip/hip_runtime.h>
#include <math.h>

namespace {
constexpr int Nn = 4, Hh = 256, Ww = 256;
constexpr int HW = Hh * Ww;
constexpr int P  = Nn * HW;          // 262144 pixels
constexpr float ZFAR  = 100.0f;
constexpr float ZNEAR = 1.0f;
constexpr float INV_SIG = 1.0f / (1e-4f + 1e-8f);   // 1/(SIGMA+1e-8)
constexpr float INV_GAM = 1e4f;                     // 1/GAMMA
constexpr float EPSF    = 1e-10f;
constexpr float INV_ZR  = 1.0f / (ZFAR - ZNEAR);
}

// pair exchange: quad_perm [1,0,3,2] swaps lanes 2i <-> 2i+1 (VALU pipe)
#define PSWAP_I(v) __builtin_amdgcn_mov_dpp((v), 0xB1, 0xf, 0xf, true)
#define PSWAP_F(v) __int_as_float(PSWAP_I(__float_as_int(v)))

#define FMA4(A, C, R)                                        \
    {                                                        \
        A.x = fmaf((C), (R).x, A.x);                         \
        A.y = fmaf((C), (R).y, A.y);                         \
        A.z = fmaf((C), (R).z, A.z);                         \
        A.w = fmaf((C), (R).w, A.w);                         \
    }

// 2 lanes per pixel: lane h owns K-slots [4h, 4h+4)
__global__ __launch_bounds__(256, 8) void render_kernel(
    const float* __restrict__ vf,     // (V,16)
    const float* __restrict__ bary,   // (P,8,3)
    const float* __restrict__ dists,  // (P,8)
    const float* __restrict__ zbuf,   // (P,8)
    const int*  __restrict__ faces,   // (F,3)
    const int*  __restrict__ p2f,     // (P,8)
    float* __restrict__ out)          // (N,17,H,W)
{
    const int t = blockIdx.x * 256 + threadIdx.x;
    const int p = t >> 1;             // pixel
    const int h = t & 1;              // K-half

    // ---- non-redundant streaming loads: own half of K (16B/lane each) ----
    const int4   f4 = *reinterpret_cast<const int4*>(p2f + (size_t)p * 8 + h * 4);
    const float4 z4 = *reinterpret_cast<const float4*>(zbuf + (size_t)p * 8 + h * 4);
    const float4 d4 = *reinterpret_cast<const float4*>(dists + (size_t)p * 8 + h * 4);

    int   fk[4] = {f4.x, f4.y, f4.z, f4.w};
    float zr[4] = {z4.x, z4.y, z4.z, z4.w};
    float dk[4] = {d4.x, d4.y, d4.z, d4.w};

    // ---- pass 1: z_inv, local max, pair-combined max ----
    float zi[4];
    float zmax = EPSF;
#pragma unroll
    for (int k = 0; k < 4; ++k) {
        const bool valid = fk[k] >= 0;
        float zv = valid ? (ZFAR - zr[k]) * INV_ZR : 0.0f;
        zi[k] = zv;
        zmax = fmaxf(zmax, zv);
    }
    zmax = fmaxf(zmax, PSWAP_F(zmax));      // pair max

    // ---- pass 2: weights, partial denom/alpha, pair-combined ----
    const float delta = fmaxf(__expf((EPSF - zmax) * INV_GAM), EPSF);
    float dsum = 0.0f;
    float keep = 1.0f;
    float wv[4];
#pragma unroll
    for (int k = 0; k < 4; ++k) {
        const bool valid = fk[k] >= 0;
        float pr = valid ? 1.0f / (1.0f + __expf(dk[k] * INV_SIG)) : 0.0f;
        keep *= (1.0f - pr);
        float w = pr * __expf((zi[k] - zmax) * INV_GAM);
        wv[k] = w;
        dsum += w;
    }
    dsum += PSWAP_F(dsum);                  // pair sum
    keep *= PSWAP_F(keep);                  // pair product
    const float denom = dsum + delta;

    // ---- gather: per-lane argmax over own 4 slots (~1 wave iteration) ----
    float4 acc0 = make_float4(0.f, 0.f, 0.f, 0.f);
    float4 acc1 = make_float4(0.f, 0.f, 0.f, 0.f);
    float4 acc2 = make_float4(0.f, 0.f, 0.f, 0.f);
    float4 acc3 = make_float4(0.f, 0.f, 0.f, 0.f);

    while (true) {
        float wb = 0.0f;
        int fsel = 0, ksel = -1;
#pragma unroll
        for (int k = 0; k < 4; ++k) {
            const bool better = wv[k] > wb;
            wb   = better ? wv[k] : wb;
            fsel = better ? fk[k] : fsel;
            ksel = better ? k : ksel;
        }
        if (!__any(wb > 0.0f)) break;

        if (wb > 0.0f) {
            const int4 vidx = *reinterpret_cast<const int4*>(faces + (size_t)fsel * 3);
            const float4 bq = *reinterpret_cast<const float4*>(
                bary + (size_t)p * 24 + h * 12 + ksel * 3);
            const float c0 = wb * bq.x;
            const float c1 = wb * bq.y;
            const float c2 = wb * bq.z;
            {
                const float4* r = reinterpret_cast<const float4*>(vf + (size_t)vidx.x * 16);
                float4 q0 = r[0], q1 = r[1], q2 = r[2], q3 = r[3];
                FMA4(acc0, c0, q0); FMA4(acc1, c0, q1);
                FMA4(acc2, c0, q2); FMA4(acc3, c0, q3);
            }
            {
                const float4* r = reinterpret_cast<const float4*>(vf + (size_t)vidx.y * 16);
                float4 q0 = r[0], q1 = r[1], q2 = r[2], q3 = r[3];
                FMA4(acc0, c1, q0); FMA4(acc1, c1, q1);
                FMA4(acc2, c1, q2); FMA4(acc3, c1, q3);
            }
            {
                const float4* r = reinterpret_cast<const float4*>(vf + (size_t)vidx.z * 16);
                float4 q0 = r[0], q1 = r[1], q2 = r[2], q3 = r[3];
                FMA4(acc0, c2, q0); FMA4(acc1, c2, q1);
                FMA4(acc2, c2, q2); FMA4(acc3, c2, q3);
            }
        }

        // clear consumed slot (static indices only)
#pragma unroll
        for (int k = 0; k < 4; ++k)
            wv[k] = (k == ksel) ? 0.0f : wv[k];
    }

    // ---- pair-combine the 16-channel accumulator (dpp + add) ----
    acc0.x += PSWAP_F(acc0.x); acc0.y += PSWAP_F(acc0.y);
    acc0.z += PSWAP_F(acc0.z); acc0.w += PSWAP_F(acc0.w);
    acc1.x += PSWAP_F(acc1.x); acc1.y += PSWAP_F(acc1.y);
    acc1.z += PSWAP_F(acc1.z); acc1.w += PSWAP_F(acc1.w);
    acc2.x += PSWAP_F(acc2.x); acc2.y += PSWAP_F(acc2.y);
    acc2.z += PSWAP_F(acc2.z); acc2.w += PSWAP_F(acc2.w);
    acc3.x += PSWAP_F(acc3.x); acc3.y += PSWAP_F(acc3.y);
    acc3.z += PSWAP_F(acc3.z); acc3.w += PSWAP_F(acc3.w);

    // ---- epilogue: lane h stores channels [8h, 8h+8) ----
    const float invden = 1.0f / denom;
    const int n  = p >> 16;           // p / HW (HW = 65536)
    const int hw = p & (HW - 1);
    float* o = out + (size_t)n * 17 * HW + (size_t)h * 8 * HW + hw;
    const float4 sa = h ? acc2 : acc0;
    const float4 sb = h ? acc3 : acc1;
    o[(size_t)0 * HW] = sa.x * invden;
    o[(size_t)1 * HW] = sa.y * invden;
    o[(size_t)2 * HW] = sa.z * invden;
    o[(size_t)3 * HW] = sa.w * invden;
    o[(size_t)4 * HW] = sb.x * invden;
    o[(size_t)5 * HW] = sb.y * invden;
    o[(size_t)6 * HW] = sb.z * invden;
    o[(size_t)7 * HW] = sb.w * invden;
    if (h == 0)
        out[(size_t)n * 17 * HW + (size_t)16 * HW + hw] = 1.0f - keep;  // alpha
}

extern "C" void kernel_launch(void* const* d_in, const int* in_sizes, int n_in,
                              void* d_out, int out_size, void* d_ws, size_t ws_size,
                              hipStream_t stream) {
    const float* vf    = (const float*)d_in[0];
    const float* bary  = (const float*)d_in[1];
    const float* dists = (const float*)d_in[2];
    const float* zbuf  = (const float*)d_in[3];
    const int*   faces = (const int*)d_in[4];
    const int*   p2f   = (const int*)d_in[5];
    float* out = (float*)d_out;

    render_kernel<<<dim3((P * 2) / 256), dim3(256), 0, stream>>>(
        vf, bary, dists, zbuf, faces, p2f, out);
}

// Round 8
// 20.759 us; speedup vs baseline: 1.2220x; 1.2220x over previous
//
#include <hip/hip_runtime.h>
#include <math.h>

namespace {
constexpr int Nn = 4, Hh = 256, Ww = 256;
constexpr int HW = Hh * Ww;
constexpr int P  = Nn * HW;          // 262144 pixels
constexpr float ZFAR  = 100.0f;
constexpr float ZNEAR = 1.0f;
constexpr float INV_SIG = 1.0f / (1e-4f + 1e-8f);   // 1/(SIGMA+1e-8)
constexpr float INV_GAM = 1e4f;                     // 1/GAMMA
constexpr float EPSF    = 1e-10f;
constexpr float INV_ZR  = 1.0f / (ZFAR - ZNEAR);
}

// quad broadcast via DPP quad_perm (VALU pipe, compile-time ctrl)
#define QB_I(v, S) __builtin_amdgcn_mov_dpp((v), ((S) * 0x55), 0xf, 0xf, true)
#define QB_F(v, S) __int_as_float(QB_I(__float_as_int(v), S))

// early gather: broadcast owner's vertex ids, issue this lane's 16B chunk loads
#define LOAD_SLOT(S, QA, QB_, QC, OK)                                          \
    {                                                                          \
        OK = QB_I(fvalid, S);                                                  \
        if (OK) {                                                              \
            const int g0 = QB_I(vx, S);                                        \
            const int g1 = QB_I(vy, S);                                        \
            const int g2 = QB_I(vz, S);                                        \
            QA = *(reinterpret_cast<const float4*>(vf + (size_t)g0 * 16) + cq); \
            QB_ = *(reinterpret_cast<const float4*>(vf + (size_t)g1 * 16) + cq); \
            QC = *(reinterpret_cast<const float4*>(vf + (size_t)g2 * 16) + cq); \
        }                                                                      \
    }

// late accumulate: broadcast owner's (now-computed) coeffs, FMA the chunks.
// coeffs are 0 when owner invalid and QA..QC are zero-init -> unguarded safe.
#define FMA_SLOT(S, QA, QB_, QC, PS)                                           \
    {                                                                          \
        const float w0 = QB_F(c0, S);                                          \
        const float w1 = QB_F(c1, S);                                          \
        const float w2 = QB_F(c2, S);                                          \
        PS.x = fmaf(w0, QA.x, fmaf(w1, QB_.x, fmaf(w2, QC.x, PS.x)));          \
        PS.y = fmaf(w0, QA.y, fmaf(w1, QB_.y, fmaf(w2, QC.y, PS.y)));          \
        PS.z = fmaf(w0, QA.z, fmaf(w1, QB_.z, fmaf(w2, QC.z, PS.z)));          \
        PS.w = fmaf(w0, QA.w, fmaf(w1, QB_.w, fmaf(w2, QC.w, PS.w)));          \
    }

// rare-path slot: load + FMA in one go (guarded on broadcast weight)
#define DO_SLOT(S, PS)                                                         \
    {                                                                          \
        const float ws = QB_F(wb2, S);                                         \
        if (ws > 0.0f) {                                                       \
            const int   g0 = QB_I(vx2, S);                                     \
            const int   g1 = QB_I(vy2, S);                                     \
            const int   g2 = QB_I(vz2, S);                                     \
            const float w0 = QB_F(e0, S);                                      \
            const float w1 = QB_F(e1, S);                                      \
            const float w2 = QB_F(e2, S);                                      \
            const float4 r0 = *(reinterpret_cast<const float4*>(vf + (size_t)g0 * 16) + cq); \
            const float4 r1 = *(reinterpret_cast<const float4*>(vf + (size_t)g1 * 16) + cq); \
            const float4 r2 = *(reinterpret_cast<const float4*>(vf + (size_t)g2 * 16) + cq); \
            PS.x = fmaf(w0, r0.x, fmaf(w1, r1.x, fmaf(w2, r2.x, PS.x)));       \
            PS.y = fmaf(w0, r0.y, fmaf(w1, r1.y, fmaf(w2, r2.y, PS.y)));       \
            PS.z = fmaf(w0, r0.z, fmaf(w1, r1.z, fmaf(w2, r2.z, PS.z)));       \
            PS.w = fmaf(w0, r0.w, fmaf(w1, r1.w, fmaf(w2, r2.w, PS.w)));       \
        }                                                                      \
    }

__global__ __launch_bounds__(256) void render_kernel(
    const float* __restrict__ vf,     // (V,16)
    const float* __restrict__ bary,   // (P,8,3)
    const float* __restrict__ dists,  // (P,8)
    const float* __restrict__ zbuf,   // (P,8)
    const int*  __restrict__ faces,   // (F,3)
    const int*  __restrict__ p2f,     // (P,8)
    float* __restrict__ out)          // (N,17,H,W)
{
    __shared__ float xp[256 * 20];    // 80B/pixel transpose scratch
    const int pp = threadIdx.x;
    const int p  = blockIdx.x * 256 + pp;
    const int cq = pp & 3;            // chunk role within quad
    const int qb = pp & ~3;           // quad base (pixel-local)

    // ---- streaming loads issued upfront ----
    const int4*   fp = reinterpret_cast<const int4*>(p2f + (size_t)p * 8);
    const float4* zp = reinterpret_cast<const float4*>(zbuf + (size_t)p * 8);
    const float4* dp = reinterpret_cast<const float4*>(dists + (size_t)p * 8);
    int4   fA = fp[0], fB = fp[1];
    float4 zA = zp[0], zB = zp[1];
    float4 dA = dp[0], dB = dp[1];

    int fk[8] = {fA.x, fA.y, fA.z, fA.w, fB.x, fB.y, fB.z, fB.w};
    float zraw[8] = {zA.x, zA.y, zA.z, zA.w, zB.x, zB.y, zB.z, zB.w};

    // ---- z_inv, zmax, AND argmax-by-z (softmax-free survivor selection) ----
    // w_k = pr_k * exp((z_k - zmax)*1e4): exp term dominates (pr ratio <= e^4,
    // z granularity 1e-4) -> argmax-z is always a w>0 survivor; any near-tie
    // survivors are caught by the rare loop. Selection needs only p2f+zbuf.
    float zi[8];
    float zmax = EPSF, zbest = 0.0f;
    int ksel = -1, fsel = 0;
#pragma unroll
    for (int k = 0; k < 8; ++k) {
        const bool valid = fk[k] >= 0;
        float zv = valid ? (ZFAR - zraw[k]) * INV_ZR : 0.0f;
        zi[k] = zv;
        zmax = fmaxf(zmax, zv);
        const bool better = valid && (zv > zbest);
        zbest = better ? zv : zbest;
        ksel  = better ? k : ksel;
        fsel  = better ? fk[k] : fsel;
    }
    const int fvalid = (ksel >= 0) ? 1 : 0;

    // ---- owner issues faces + bary for the selected slot immediately ----
    int vx = 0, vy = 0, vz = 0;
    float b0 = 0.0f, b1 = 0.0f, b2 = 0.0f;
    if (fvalid) {
        const int4 vidx = *reinterpret_cast<const int4*>(faces + (size_t)fsel * 3);
        const float4 bq = *reinterpret_cast<const float4*>(bary + (size_t)p * 24 + ksel * 3);
        vx = vidx.x; vy = vidx.y; vz = vidx.z;
        b0 = bq.x; b1 = bq.y; b2 = bq.z;
    }

    // ---- early vf chunk loads for all 4 quad slots (before softmax) ----
    float4 z4 = make_float4(0.f, 0.f, 0.f, 0.f);
    float4 q0a = z4, q0b = z4, q0c = z4;
    float4 q1a = z4, q1b = z4, q1c = z4;
    float4 q2a = z4, q2b = z4, q2c = z4;
    float4 q3a = z4, q3b = z4, q3c = z4;
    int ok0, ok1, ok2, ok3;
    LOAD_SLOT(0, q0a, q0b, q0c, ok0)
    LOAD_SLOT(1, q1a, q1b, q1c, ok1)
    LOAD_SLOT(2, q2a, q2b, q2c, ok2)
    LOAD_SLOT(3, q3a, q3b, q3c, ok3)
    (void)ok0; (void)ok1; (void)ok2; (void)ok3;

    // ---- softmax (overlaps the gather loads' latency) ----
    float dk[8] = {dA.x, dA.y, dA.z, dA.w, dB.x, dB.y, dB.z, dB.w};
    const float delta = fmaxf(__expf((EPSF - zmax) * INV_GAM), EPSF);
    float denom = delta;
    float keep  = 1.0f;
    float wv[8];
#pragma unroll
    for (int k = 0; k < 8; ++k) {
        const bool valid = fk[k] >= 0;
        float pr = valid ? 1.0f / (1.0f + __expf(dk[k] * INV_SIG)) : 0.0f;
        keep *= (1.0f - pr);
        float w = pr * __expf((zi[k] - zmax) * INV_GAM);
        wv[k] = w;
        denom += w;
    }

    // wb = wv[ksel] via static cndmask chain
    float wb = 0.0f;
#pragma unroll
    for (int k = 0; k < 8; ++k) wb = (k == ksel) ? wv[k] : wb;
    const float c0 = wb * b0, c1 = wb * b1, c2 = wb * b2;

    // ---- accumulate the prefetched slot data ----
    float4 ps0 = z4, ps1 = z4, ps2 = z4, ps3 = z4;
    FMA_SLOT(0, q0a, q0b, q0c, ps0)
    FMA_SLOT(1, q1a, q1b, q1c, ps1)
    FMA_SLOT(2, q2a, q2b, q2c, ps2)
    FMA_SLOT(3, q3a, q3b, q3c, ps3)

    // ---- rare path: remaining w>0 slots (near-ties only) ----
#pragma unroll
    for (int k = 0; k < 8; ++k) wv[k] = (k == ksel) ? 0.0f : wv[k];
    bool more = false;
#pragma unroll
    for (int k = 0; k < 8; ++k) more = more || (wv[k] > 0.0f);

    if (__any(more)) {
        while (true) {
            float wb2 = 0.0f;
            int fsel2 = 0, ksel2 = -1;
#pragma unroll
            for (int k = 0; k < 8; ++k) {
                const bool better = wv[k] > wb2;
                wb2   = better ? wv[k] : wb2;
                fsel2 = better ? fk[k] : fsel2;
                ksel2 = better ? k : ksel2;
            }
            if (!__any(wb2 > 0.0f)) break;

            int vx2 = 0, vy2 = 0, vz2 = 0;
            float e0 = 0.0f, e1 = 0.0f, e2 = 0.0f;
            if (wb2 > 0.0f) {
                const int4 vidx = *reinterpret_cast<const int4*>(faces + (size_t)fsel2 * 3);
                const float4 bq = *reinterpret_cast<const float4*>(
                    bary + (size_t)p * 24 + ksel2 * 3);
                vx2 = vidx.x; vy2 = vidx.y; vz2 = vidx.z;
                e0 = wb2 * bq.x; e1 = wb2 * bq.y; e2 = wb2 * bq.z;
            }
            DO_SLOT(0, ps0)
            DO_SLOT(1, ps1)
            DO_SLOT(2, ps2)
            DO_SLOT(3, ps3)
#pragma unroll
            for (int k = 0; k < 8; ++k)
                wv[k] = (k == ksel2) ? 0.0f : wv[k];
        }
    }

    // ---- 4x4 quad transpose via LDS: distributed chunks -> per-pixel ----
    *reinterpret_cast<float4*>(&xp[(qb + 0) * 20 + cq * 4]) = ps0;
    *reinterpret_cast<float4*>(&xp[(qb + 1) * 20 + cq * 4]) = ps1;
    *reinterpret_cast<float4*>(&xp[(qb + 2) * 20 + cq * 4]) = ps2;
    *reinterpret_cast<float4*>(&xp[(qb + 3) * 20 + cq * 4]) = ps3;
    __syncthreads();
    const float4 a0 = *reinterpret_cast<const float4*>(&xp[pp * 20 + 0]);
    const float4 a1 = *reinterpret_cast<const float4*>(&xp[pp * 20 + 4]);
    const float4 a2 = *reinterpret_cast<const float4*>(&xp[pp * 20 + 8]);
    const float4 a3 = *reinterpret_cast<const float4*>(&xp[pp * 20 + 12]);

    // ---- epilogue: divide by denom, store channel-major ----
    const float invden = 1.0f / denom;
    const int n  = p >> 16;           // p / HW (HW = 65536)
    const int hw = p & (HW - 1);
    float* o = out + (size_t)n * 17 * HW + hw;
    o[(size_t)0  * HW] = a0.x * invden;
    o[(size_t)1  * HW] = a0.y * invden;
    o[(size_t)2  * HW] = a0.z * invden;
    o[(size_t)3  * HW] = a0.w * invden;
    o[(size_t)4  * HW] = a1.x * invden;
    o[(size_t)5  * HW] = a1.y * invden;
    o[(size_t)6  * HW] = a1.z * invden;
    o[(size_t)7  * HW] = a1.w * invden;
    o[(size_t)8  * HW] = a2.x * invden;
    o[(size_t)9  * HW] = a2.y * invden;
    o[(size_t)10 * HW] = a2.z * invden;
    o[(size_t)11 * HW] = a2.w * invden;
    o[(size_t)12 * HW] = a3.x * invden;
    o[(size_t)13 * HW] = a3.y * invden;
    o[(size_t)14 * HW] = a3.z * invden;
    o[(size_t)15 * HW] = a3.w * invden;
    o[(size_t)16 * HW] = 1.0f - keep;   // alpha
}

extern "C" void kernel_launch(void* const* d_in, const int* in_sizes, int n_in,
                              void* d_out, int out_size, void* d_ws, size_t ws_size,
                              hipStream_t stream) {
    const float* vf    = (const float*)d_in[0];
    const float* bary  = (const float*)d_in[1];
    const float* dists = (const float*)d_in[2];
    const float* zbuf  = (const float*)d_in[3];
    const int*   faces = (const int*)d_in[4];
    const int*   p2f   = (const int*)d_in[5];
    float* out = (float*)d_out;

    render_kernel<<<dim3(P / 256), dim3(256), 0, stream>>>(
        vf, bary, dists, zbuf, faces, p2f, out);
}

// Round 9
// 20.520 us; speedup vs baseline: 1.2362x; 1.0116x over previous
//
#include <hip/hip_runtime.h>
#include <math.h>

namespace {
constexpr int Nn = 4, Hh = 256, Ww = 256;
constexpr int HW = Hh * Ww;
constexpr int P  = Nn * HW;          // 262144 pixels
constexpr float ZFAR  = 100.0f;
constexpr float ZNEAR = 1.0f;
constexpr float INV_SIG = 1.0f / (1e-4f + 1e-8f);   // 1/(SIGMA+1e-8)
constexpr float INV_GAM = 1e4f;                     // 1/GAMMA
constexpr float EPSF    = 1e-10f;
constexpr float INV_ZR  = 1.0f / (ZFAR - ZNEAR);
}

// quad broadcast via DPP quad_perm (VALU pipe, compile-time ctrl)
#define QB_I(v, S) __builtin_amdgcn_mov_dpp((v), ((S) * 0x55), 0xf, 0xf, true)
#define QB_F(v, S) __int_as_float(QB_I(__float_as_int(v), S))

// early gather: broadcast owner's vertex ids, issue this lane's 16B chunk loads
#define LOAD_SLOT(S, QA, QB_, QC)                                              \
    {                                                                          \
        if (QB_I(fvalid, S)) {                                                 \
            const int g0 = QB_I(vx, S);                                        \
            const int g1 = QB_I(vy, S);                                        \
            const int g2 = QB_I(vz, S);                                        \
            QA = *(reinterpret_cast<const float4*>(vf + (size_t)g0 * 16) + cq); \
            QB_ = *(reinterpret_cast<const float4*>(vf + (size_t)g1 * 16) + cq); \
            QC = *(reinterpret_cast<const float4*>(vf + (size_t)g2 * 16) + cq); \
        }                                                                      \
    }

// late accumulate: broadcast owner's (now-computed) coeffs, FMA the chunks.
// coeffs are 0 when owner invalid and QA..QC are zero-init -> unguarded safe.
#define FMA_SLOT(S, QA, QB_, QC, PS)                                           \
    {                                                                          \
        const float w0 = QB_F(c0, S);                                          \
        const float w1 = QB_F(c1, S);                                          \
        const float w2 = QB_F(c2, S);                                          \
        PS.x = fmaf(w0, QA.x, fmaf(w1, QB_.x, fmaf(w2, QC.x, PS.x)));          \
        PS.y = fmaf(w0, QA.y, fmaf(w1, QB_.y, fmaf(w2, QC.y, PS.y)));          \
        PS.z = fmaf(w0, QA.z, fmaf(w1, QB_.z, fmaf(w2, QC.z, PS.z)));          \
        PS.w = fmaf(w0, QA.w, fmaf(w1, QB_.w, fmaf(w2, QC.w, PS.w)));          \
    }

// rare-path slot: load + FMA in one go (guarded on broadcast weight)
#define DO_SLOT(S, PS)                                                         \
    {                                                                          \
        const float ws = QB_F(wb2, S);                                         \
        if (ws > 0.0f) {                                                       \
            const int   g0 = QB_I(vx2, S);                                     \
            const int   g1 = QB_I(vy2, S);                                     \
            const int   g2 = QB_I(vz2, S);                                     \
            const float w0 = QB_F(e0, S);                                      \
            const float w1 = QB_F(e1, S);                                      \
            const float w2 = QB_F(e2, S);                                      \
            const float4 r0 = *(reinterpret_cast<const float4*>(vf + (size_t)g0 * 16) + cq); \
            const float4 r1 = *(reinterpret_cast<const float4*>(vf + (size_t)g1 * 16) + cq); \
            const float4 r2 = *(reinterpret_cast<const float4*>(vf + (size_t)g2 * 16) + cq); \
            PS.x = fmaf(w0, r0.x, fmaf(w1, r1.x, fmaf(w2, r2.x, PS.x)));       \
            PS.y = fmaf(w0, r0.y, fmaf(w1, r1.y, fmaf(w2, r2.y, PS.y)));       \
            PS.z = fmaf(w0, r0.z, fmaf(w1, r1.z, fmaf(w2, r2.z, PS.z)));       \
            PS.w = fmaf(w0, r0.w, fmaf(w1, r1.w, fmaf(w2, r2.w, PS.w)));       \
        }                                                                      \
    }

// __launch_bounds__(256, 4): 4 waves/EU min -> VGPR cap 128 so all 4
// grid-supplied waves/SIMD are co-resident (m69: waves halve past 128 VGPR)
__global__ __launch_bounds__(256, 4) void render_kernel(
    const float* __restrict__ vf,     // (V,16)
    const float* __restrict__ bary,   // (P,8,3)
    const float* __restrict__ dists,  // (P,8)
    const float* __restrict__ zbuf,   // (P,8)
    const int*  __restrict__ faces,   // (F,3)
    const int*  __restrict__ p2f,     // (P,8)
    float* __restrict__ out)          // (N,17,H,W)
{
    __shared__ float xp[256 * 20];    // 80B/pixel transpose scratch
    const int pp = threadIdx.x;
    const int p  = blockIdx.x * 256 + pp;
    const int cq = pp & 3;            // chunk role within quad
    const int qb = pp & ~3;           // quad base (pixel-local)

    // ---- streaming loads issued upfront ----
    const int4*   fp = reinterpret_cast<const int4*>(p2f + (size_t)p * 8);
    const float4* zp = reinterpret_cast<const float4*>(zbuf + (size_t)p * 8);
    const float4* dp = reinterpret_cast<const float4*>(dists + (size_t)p * 8);
    int4   fA = fp[0], fB = fp[1];
    float4 zA = zp[0], zB = zp[1];
    float4 dA = dp[0], dB = dp[1];

    int fk[8] = {fA.x, fA.y, fA.z, fA.w, fB.x, fB.y, fB.z, fB.w};
    float zraw[8] = {zA.x, zA.y, zA.z, zA.w, zB.x, zB.y, zB.z, zB.w};

    // ---- z_inv, zmax, argmax-by-z (softmax-free survivor selection) ----
    float zi[8];
    float zmax = EPSF, zbest = 0.0f;
    int ksel = -1, fsel = 0;
#pragma unroll
    for (int k = 0; k < 8; ++k) {
        const bool valid = fk[k] >= 0;
        float zv = valid ? (ZFAR - zraw[k]) * INV_ZR : 0.0f;
        zi[k] = zv;
        zmax = fmaxf(zmax, zv);
        const bool better = valid && (zv > zbest);
        zbest = better ? zv : zbest;
        ksel  = better ? k : ksel;
        fsel  = better ? fk[k] : fsel;
    }
    const int fvalid = (ksel >= 0) ? 1 : 0;

    // ---- owner issues faces + bary for the selected slot immediately ----
    int vx = 0, vy = 0, vz = 0;
    float b0 = 0.0f, b1 = 0.0f, b2 = 0.0f;
    if (fvalid) {
        const int4 vidx = *reinterpret_cast<const int4*>(faces + (size_t)fsel * 3);
        const float4 bq = *reinterpret_cast<const float4*>(bary + (size_t)p * 24 + ksel * 3);
        vx = vidx.x; vy = vidx.y; vz = vidx.z;
        b0 = bq.x; b1 = bq.y; b2 = bq.z;
    }

    // ---- staggered early vf loads: slots 0-1 before softmax (fully hidden),
    //      slots 2-3 interleaved with FMA (keeps peak q-regs at ~24 VGPR) ----
    const float4 z4 = make_float4(0.f, 0.f, 0.f, 0.f);
    float4 q0a = z4, q0b = z4, q0c = z4;
    float4 q1a = z4, q1b = z4, q1c = z4;
    LOAD_SLOT(0, q0a, q0b, q0c)
    LOAD_SLOT(1, q1a, q1b, q1c)

    // ---- softmax (overlaps slot 0-1 gather latency) ----
    float dk[8] = {dA.x, dA.y, dA.z, dA.w, dB.x, dB.y, dB.z, dB.w};
    const float delta = fmaxf(__expf((EPSF - zmax) * INV_GAM), EPSF);
    float denom = delta;
    float keep  = 1.0f;
    float wv[8];
#pragma unroll
    for (int k = 0; k < 8; ++k) {
        const bool valid = fk[k] >= 0;
        float pr = valid ? 1.0f / (1.0f + __expf(dk[k] * INV_SIG)) : 0.0f;
        keep *= (1.0f - pr);
        float w = pr * __expf((zi[k] - zmax) * INV_GAM);
        wv[k] = w;
        denom += w;
    }

    // wb = wv[ksel] via static cndmask chain
    float wb = 0.0f;
#pragma unroll
    for (int k = 0; k < 8; ++k) wb = (k == ksel) ? wv[k] : wb;
    const float c0 = wb * b0, c1 = wb * b1, c2 = wb * b2;

    // ---- interleaved FMA / LOAD: retire slot regs before loading next ----
    float4 ps0 = z4, ps1 = z4, ps2 = z4, ps3 = z4;
    FMA_SLOT(0, q0a, q0b, q0c, ps0)
    float4 q2a = z4, q2b = z4, q2c = z4;
    LOAD_SLOT(2, q2a, q2b, q2c)
    FMA_SLOT(1, q1a, q1b, q1c, ps1)
    float4 q3a = z4, q3b = z4, q3c = z4;
    LOAD_SLOT(3, q3a, q3b, q3c)
    FMA_SLOT(2, q2a, q2b, q2c, ps2)
    FMA_SLOT(3, q3a, q3b, q3c, ps3)

    // ---- rare path: remaining w>0 slots (near-ties only) ----
#pragma unroll
    for (int k = 0; k < 8; ++k) wv[k] = (k == ksel) ? 0.0f : wv[k];
    bool more = false;
#pragma unroll
    for (int k = 0; k < 8; ++k) more = more || (wv[k] > 0.0f);

    if (__any(more)) {
        while (true) {
            float wb2 = 0.0f;
            int fsel2 = 0, ksel2 = -1;
#pragma unroll
            for (int k = 0; k < 8; ++k) {
                const bool better = wv[k] > wb2;
                wb2   = better ? wv[k] : wb2;
                fsel2 = better ? fk[k] : fsel2;
                ksel2 = better ? k : ksel2;
            }
            if (!__any(wb2 > 0.0f)) break;

            int vx2 = 0, vy2 = 0, vz2 = 0;
            float e0 = 0.0f, e1 = 0.0f, e2 = 0.0f;
            if (wb2 > 0.0f) {
                const int4 vidx = *reinterpret_cast<const int4*>(faces + (size_t)fsel2 * 3);
                const float4 bq = *reinterpret_cast<const float4*>(
                    bary + (size_t)p * 24 + ksel2 * 3);
                vx2 = vidx.x; vy2 = vidx.y; vz2 = vidx.z;
                e0 = wb2 * bq.x; e1 = wb2 * bq.y; e2 = wb2 * bq.z;
            }
            DO_SLOT(0, ps0)
            DO_SLOT(1, ps1)
            DO_SLOT(2, ps2)
            DO_SLOT(3, ps3)
#pragma unroll
            for (int k = 0; k < 8; ++k)
                wv[k] = (k == ksel2) ? 0.0f : wv[k];
        }
    }

    // ---- 4x4 quad transpose via LDS: distributed chunks -> per-pixel ----
    *reinterpret_cast<float4*>(&xp[(qb + 0) * 20 + cq * 4]) = ps0;
    *reinterpret_cast<float4*>(&xp[(qb + 1) * 20 + cq * 4]) = ps1;
    *reinterpret_cast<float4*>(&xp[(qb + 2) * 20 + cq * 4]) = ps2;
    *reinterpret_cast<float4*>(&xp[(qb + 3) * 20 + cq * 4]) = ps3;
    __syncthreads();
    const float4 a0 = *reinterpret_cast<const float4*>(&xp[pp * 20 + 0]);
    const float4 a1 = *reinterpret_cast<const float4*>(&xp[pp * 20 + 4]);
    const float4 a2 = *reinterpret_cast<const float4*>(&xp[pp * 20 + 8]);
    const float4 a3 = *reinterpret_cast<const float4*>(&xp[pp * 20 + 12]);

    // ---- epilogue: divide by denom, store channel-major ----
    const float invden = 1.0f / denom;
    const int n  = p >> 16;           // p / HW (HW = 65536)
    const int hw = p & (HW - 1);
    float* o = out + (size_t)n * 17 * HW + hw;
    o[(size_t)0  * HW] = a0.x * invden;
    o[(size_t)1  * HW] = a0.y * invden;
    o[(size_t)2  * HW] = a0.z * invden;
    o[(size_t)3  * HW] = a0.w * invden;
    o[(size_t)4  * HW] = a1.x * invden;
    o[(size_t)5  * HW] = a1.y * invden;
    o[(size_t)6  * HW] = a1.z * invden;
    o[(size_t)7  * HW] = a1.w * invden;
    o[(size_t)8  * HW] = a2.x * invden;
    o[(size_t)9  * HW] = a2.y * invden;
    o[(size_t)10 * HW] = a2.z * invden;
    o[(size_t)11 * HW] = a2.w * invden;
    o[(size_t)12 * HW] = a3.x * invden;
    o[(size_t)13 * HW] = a3.y * invden;
    o[(size_t)14 * HW] = a3.z * invden;
    o[(size_t)15 * HW] = a3.w * invden;
    o[(size_t)16 * HW] = 1.0f - keep;   // alpha
}

extern "C" void kernel_launch(void* const* d_in, const int* in_sizes, int n_in,
                              void* d_out, int out_size, void* d_ws, size_t ws_size,
                              hipStream_t stream) {
    const float* vf    = (const float*)d_in[0];
    const float* bary  = (const float*)d_in[1];
    const float* dists = (const float*)d_in[2];
    const float* zbuf  = (const float*)d_in[3];
    const int*   faces = (const int*)d_in[4];
    const int*   p2f   = (const int*)d_in[5];
    float* out = (float*)d_out;

    render_kernel<<<dim3(P / 256), dim3(256), 0, stream>>>(
        vf, bary, dists, zbuf, faces, p2f, out);
}